// Round 18
// baseline (399.305 us; speedup 1.0000x reference)
//
#include <hip/hip_runtime.h>
#include <hip/hip_bf16.h>

typedef unsigned short u16;
typedef short bf16x8 __attribute__((ext_vector_type(8)));
typedef float f32x4 __attribute__((ext_vector_type(4)));
typedef unsigned short u16x8 __attribute__((ext_vector_type(8)));

#define HW 784
#define PLANE 200704      // 256*784
#define PADPX 900         // 30*30 padded image

// ws layout (bytes)
#define OFF_PX   0          // 128*256 f32
#define OFF_Y3   131072     // 2048 f32
#define OFF_GL   262144     // 128*256 f32 (1+sigmoid)
#define OFF_WT   393216     // 9*8*256*32 bf16 = 1,179,648
#define OFF_XSTG 1572864    // 128*900*256 bf16 = 58,982,400

__device__ __forceinline__ u16 f2b(float f) {
    union { float f; unsigned u; } v; v.f = f;
    unsigned r = v.u + 0x7FFF + ((v.u >> 16) & 1);   // RNE
    return (u16)(r >> 16);
}

typedef __attribute__((address_space(1))) const unsigned int gas_u32;
typedef __attribute__((address_space(3))) unsigned int las_u32;
__device__ __forceinline__ void gload16(const void* g, void* l) {
    __builtin_amdgcn_global_load_lds((gas_u32*)g, (las_u32*)l, 16, 0, 0);
}

// ---------------- k_prep: 3 independent roles split by blockIdx.x
__global__ __launch_bounds__(256) void k_prep(const float* __restrict__ netw, u16* __restrict__ wt,
                                              u16* __restrict__ xstg,
                                              const float* __restrict__ x, float* __restrict__ px) {
    const int bx = blockIdx.x, tid = threadIdx.x;
    if (bx < 2304) {
        int id = bx * 256 + tid;
        int cl = id & 31, co = (id >> 5) & 255, cb = (id >> 13) & 7, tap = id >> 16;
        int ci = cb * 32 + cl;
        wt[id] = f2b(netw[((size_t)co * 256 + ci) * 9 + tap]);
    } else if (bx < 2432) {
        const int nt = bx - 2304;
        for (int it = 0; it < 15; ++it) {
            int cid = it * 256 + tid;
            if (cid < 3712) {
                int pxi = cid >> 5, ch = cid & 31;
                int pidx;
                if (pxi < 30) pidx = pxi;
                else if (pxi < 60) pidx = 29 * 30 + (pxi - 30);
                else { int k = pxi - 60; pidx = (1 + (k >> 1)) * 30 + (k & 1) * 29; }
                *(u16x8*)(xstg + ((size_t)nt * PADPX + pidx) * 256 + ch * 8) = (u16x8){0,0,0,0,0,0,0,0};
            }
        }
    } else {
        const int idx = bx - 2432;
        const int nt = idx >> 2, cg = idx & 3;
        const int wv = tid >> 6, ln = tid & 63;
        for (int i = 0; i < 16; ++i) {
            int c = cg * 64 + wv * 16 + i;
            const float4* xp = (const float4*)(x + (size_t)nt * PLANE + (size_t)c * HW);
            float s = 0.f;
            for (int k = ln; k < 196; k += 64) { float4 v = xp[k]; s += v.x + v.y + v.z + v.w; }
            #pragma unroll
            for (int o = 32; o; o >>= 1) s += __shfl_xor(s, o);
            if (ln == 0) px[nt * 256 + c] = s * (1.f / 784.f);
        }
    }
}

// ---------------- k_sea: 256 blocks = (b, o). Thread = c2. Shift px (shift∘pool==pool∘shift),
// se_conv1d over the faithful [C'][T'] view, tree-reduce over c2.
__global__ __launch_bounds__(256) void k_sea(const float* __restrict__ px,
                                             const float* __restrict__ taw,
                                             const float* __restrict__ wse,
                                             float* __restrict__ y3) {
    const int b = blockIdx.x, o = blockIdx.y;
    const int tid = threadIdx.x;           // = c2
    __shared__ float ps_t[8 * 260];        // [t][c2], pitch 260 (bank-spread)
    __shared__ float red[4][8];
    #pragma unroll
    for (int i = 0; i < 8; ++i) {
        int e = i * 256 + tid;
        int nt = b * 8 + i;
        int c = tid;
        float v = taw[c * 3 + 1] * px[nt * 256 + c];
        if (i > 0) v += taw[c * 3] * px[(nt - 1) * 256 + c];
        if (i < 7) v += taw[c * 3 + 2] * px[(nt + 1) * 256 + c];
        ps_t[(e & 7) * 260 + (e >> 3)] = v;
    }
    __syncthreads();
    const float w0 = wse[(o * 256 + tid) * 3];
    const float w1 = wse[(o * 256 + tid) * 3 + 1];
    const float w2 = wse[(o * 256 + tid) * 3 + 2];
    float v[8];
    #pragma unroll
    for (int t = 0; t < 8; ++t) {
        float a = w1 * ps_t[t * 260 + tid];
        if (t > 0) a += w0 * ps_t[(t - 1) * 260 + tid];
        if (t < 7) a += w2 * ps_t[(t + 1) * 260 + tid];
        v[t] = a;
    }
    #pragma unroll
    for (int t = 0; t < 8; ++t) {
        float s = v[t];
        #pragma unroll
        for (int off = 32; off; off >>= 1) s += __shfl_xor(s, off);
        v[t] = s;
    }
    const int wv = tid >> 6, ln = tid & 63;
    if (ln == 0) {
        #pragma unroll
        for (int t = 0; t < 8; ++t) red[wv][t] = v[t];
    }
    __syncthreads();
    if (tid < 8)
        y3[b * 128 + o * 8 + tid] = red[0][tid] + red[1][tid] + red[2][tid] + red[3][tid];
}

// ---------------- k_seb: BN(batch stats) + relu + 1x1 + sigmoid -> gl = 1+sigmoid
__global__ __launch_bounds__(256) void k_seb(const float* __restrict__ y3,
                                             const float* __restrict__ gamma,
                                             const float* __restrict__ beta,
                                             const float* __restrict__ w1,
                                             float* __restrict__ gl) {
    const int b = blockIdx.x, tid = threadIdx.x;
    __shared__ float y3_l[2048];
    __shared__ float sc[16], bi[16];
    __shared__ float yb[128];
    for (int i = tid; i < 2048; i += 256) y3_l[i] = y3[i];
    __syncthreads();
    if (tid < 16) {
        float s = 0.f, sq = 0.f;
        for (int i = 0; i < 128; ++i) {
            float v = y3_l[(i >> 3) * 128 + tid * 8 + (i & 7)];
            s += v; sq += v * v;
        }
        float m = s * (1.f / 128.f);
        float var = sq * (1.f / 128.f) - m * m;
        float rs = rsqrtf(var + 1e-5f) * gamma[tid];
        sc[tid] = rs; bi[tid] = beta[tid] - m * rs;
    }
    __syncthreads();
    if (tid < 128) {
        int oo = tid >> 3;
        yb[tid] = fmaxf(y3_l[b * 128 + tid] * sc[oo] + bi[oo], 0.f);
    }
    __syncthreads();
    float w1r[16];
    #pragma unroll
    for (int oo = 0; oo < 16; ++oo) w1r[oo] = w1[tid * 16 + oo];
    #pragma unroll
    for (int t = 0; t < 8; ++t) {
        float a = 0.f;
        #pragma unroll
        for (int oo = 0; oo < 16; ++oo) a += w1r[oo] * yb[oo * 8 + t];
        gl[b * 2048 + tid * 8 + t] = 1.f + 1.f / (1.f + __expf(-a));
    }
}

// ---------------- k_fused: temporal shift + gate + transpose -> xstg (q-slot XOR-swizzled
// within each 64B cb-block; coalescing unchanged). Read side un-swizzles in k_conv.
__global__ __launch_bounds__(256) void k_fused(const float* __restrict__ x,
                                               const float* __restrict__ taw,
                                               const float* __restrict__ gl,
                                               u16* __restrict__ xstg) {
    const int pt = blockIdx.x;      // 0..13 (56-pixel strips = 2 rows)
    const int nt = blockIdx.y;
    const int tid = threadIdx.x, wv = tid >> 6, ln = tid & 63;
    const int p0 = pt * 56;
    const int tseg = nt & 7;
    __shared__ float taw_l[768];
    __shared__ float gl_l[256];
    __shared__ __align__(16) u16 xs_l[256 * 57];   // pitch 57: gather lane-stride 4 mod 32
    for (int i = tid; i < 768; i += 256) taw_l[i] = taw[i];
    gl_l[tid] = gl[nt * 256 + tid];
    __syncthreads();
    const int g = ln >> 4;          // 16-lane group -> channel
    const int l = ln & 15;          // float4 index within strip
    const bool act = l < 14;
    for (int j = 0; j < 16; ++j) {
        const int c = j * 16 + wv * 4 + g;
        const float w0 = taw_l[c * 3], w1 = taw_l[c * 3 + 1], w2 = taw_l[c * 3 + 2];
        const float gc = gl_l[c];
        const float* xb = x + (size_t)nt * PLANE + (size_t)c * HW + p0;
        float4 v0 = {0, 0, 0, 0}, vm = {0, 0, 0, 0}, vp = {0, 0, 0, 0};
        if (act) {
            if (w1 != 0.f) v0 = *(const float4*)(xb + l * 4);
            if (w0 != 0.f && tseg > 0) vm = *(const float4*)(xb - PLANE + l * 4);
            if (w2 != 0.f && tseg < 7) vp = *(const float4*)(xb + PLANE + l * 4);
        }
        if (act) {
            xs_l[c * 57 + l * 4 + 0] = f2b((w0 * vm.x + w1 * v0.x + w2 * vp.x) * gc);
            xs_l[c * 57 + l * 4 + 1] = f2b((w0 * vm.y + w1 * v0.y + w2 * vp.y) * gc);
            xs_l[c * 57 + l * 4 + 2] = f2b((w0 * vm.z + w1 * v0.z + w2 * vp.z) * gc);
            xs_l[c * 57 + l * 4 + 3] = f2b((w0 * vm.w + w1 * v0.w + w2 * vp.w) * gc);
        }
    }
    __syncthreads();
    for (int k = 0; k < 7; ++k) {
        int id = k * 256 + tid;        // 0..1791
        int pp = id >> 5;              // 0..55
        int slot = id & 31;            // 16B q-slot (cb = slot>>2, q = slot&3)
        int c0 = slot * 8;
        u16x8 v;
        #pragma unroll
        for (int i = 0; i < 8; ++i) v[i] = xs_l[(c0 + i) * 57 + pp];
        int gp = p0 + pp;
        int r = gp / 28, cc = gp % 28;
        int pidx = (r + 1) * 30 + (cc + 1);
        int f = (pidx >> 1) & 3;
        int wslot = (slot & ~3) | ((slot ^ f) & 3);   // XOR within the 64B cb-block
        *(u16x8*)(xstg + ((size_t)nt * PADPX + pidx) * 256 + wslot * 8) = v;
    }
}

// ---------------- k_conv: round-14 winner + swizzled LDS reads (un-XOR on read).
// Stage reads stay LINEAR (coalescing preserved); bare vmcnt(0) fence (no clobber).
__global__ __launch_bounds__(256, 3) void k_conv(const u16* __restrict__ xstg,
                                                 const u16* __restrict__ wt,
                                                 const float* __restrict__ netb,
                                                 float* __restrict__ out) {
    const int pt = blockIdx.x;   // 0..6 : 4 output rows (112 px)
    const int mt = blockIdx.y;   // 0..1 : 128 c_out half
    const int nt = blockIdx.z;   // 0..127
    const int tid = threadIdx.x, wv = tid >> 6, ln = tid & 63;
    __shared__ __align__(16) u16 z_l[2][6144];   // [pix 192][4 x 16B q-slots]
    const int qg = ln >> 4;
    const int p = ln & 15;
    const int g8 = qg * 8;
    int pb[7];
    #pragma unroll
    for (int nf = 0; nf < 7; ++nf) {
        int n = nf * 16 + p;
        pb[nf] = (n / 28) * 30 + (n % 28);     // padded base pos
    }
    f32x4 acc[2][7];
    #pragma unroll
    for (int a = 0; a < 2; ++a)
        #pragma unroll
        for (int b = 0; b < 7; ++b) acc[a][b] = (f32x4){0.f, 0.f, 0.f, 0.f};

    const size_t gbase = ((size_t)nt * PADPX + pt * 120) * 256;   // u16 units
    const int maxpix = 899 - pt * 120;
    int pixl[3], ql[3];
    #pragma unroll
    for (int s = 0; s < 3; ++s) {
        int chunk = (wv * 3 + s) * 64 + ln;
        int px_ = chunk >> 2;
        ql[s] = chunk & 3;
        pixl[s] = px_ < maxpix ? px_ : maxpix;
    }

    auto stage = [&](int cb, int buf) {
        #pragma unroll
        for (int s = 0; s < 3; ++s) {
            const u16* g = xstg + gbase + (size_t)pixl[s] * 256 + cb * 32 + ql[s] * 8;
            gload16(g, &z_l[buf][(wv * 3 + s) * 512]);
        }
    };
    auto aload = [&](int tap, int cb, bf16x8* af) {
        const u16* ab = wt + (((size_t)tap * 8 + cb) * 256 + mt * 128 + wv * 32) * 32;
        af[0] = *(const bf16x8*)(ab + p * 32 + g8);
        af[1] = *(const bf16x8*)(ab + (16 + p) * 32 + g8);
    };

    bf16x8 afc[2], afn[2];
    aload(0, 0, afc);
    stage(0, 0);
    for (int cb = 0; cb < 8; ++cb) {
        asm volatile("s_waitcnt vmcnt(0)");    // drain gload_lds before barrier (no clobber)
        __syncthreads();
        if (cb < 7) stage(cb + 1, (cb + 1) & 1);
        const u16* zl = z_l[cb & 1];
        #pragma unroll
        for (int tap = 0; tap < 9; ++tap) {
            if (tap < 8) aload(tap + 1, cb, afn);
            else if (cb < 7) aload(0, cb + 1, afn);
            const int po = (tap / 3) * 30 + (tap % 3);
            __builtin_amdgcn_s_setprio(1);
            #pragma unroll
            for (int nf = 0; nf < 7; ++nf) {
                const int pos = pb[nf] + po;
                const int slot = (qg ^ (pos >> 1)) & 3;   // un-swizzle on read
                bf16x8 bf = *(const bf16x8*)&zl[pos * 32 + slot * 8];
                acc[0][nf] = __builtin_amdgcn_mfma_f32_16x16x32_bf16(afc[0], bf, acc[0][nf], 0, 0, 0);
                acc[1][nf] = __builtin_amdgcn_mfma_f32_16x16x32_bf16(afc[1], bf, acc[1][nf], 0, 0, 0);
            }
            __builtin_amdgcn_s_setprio(0);
            afc[0] = afn[0]; afc[1] = afn[1];
        }
    }
    // epilogue: D layout col=lane&15, row=(lane>>4)*4+i
    const int colp = ln & 15, rowp = (ln >> 4) * 4;
    const int o0 = pt * 112;
    #pragma unroll
    for (int mf = 0; mf < 2; ++mf) {
        #pragma unroll
        for (int i = 0; i < 4; ++i) {
            int co = mt * 128 + wv * 32 + mf * 16 + rowp + i;
            float bias = netb[co];
            float* ob = out + ((size_t)nt * 256 + co) * HW + o0;
            #pragma unroll
            for (int nf = 0; nf < 7; ++nf)
                ob[nf * 16 + colp] = acc[mf][nf][i] + bias;
        }
    }
}

extern "C" void kernel_launch(void* const* d_in, const int* in_sizes, int n_in,
                              void* d_out, int out_size, void* d_ws, size_t ws_size,
                              hipStream_t stream) {
    const float* x     = (const float*)d_in[0];
    const float* taw   = (const float*)d_in[1];
    const float* wse   = (const float*)d_in[2];
    const float* gamma = (const float*)d_in[3];
    const float* beta  = (const float*)d_in[4];
    const float* w1    = (const float*)d_in[5];
    const float* netw  = (const float*)d_in[6];
    const float* netb  = (const float*)d_in[7];
    float* out = (float*)d_out;
    char* ws = (char*)d_ws;
    float* px   = (float*)(ws + OFF_PX);
    float* y3   = (float*)(ws + OFF_Y3);
    float* gl   = (float*)(ws + OFF_GL);
    u16*   wt   = (u16*)(ws + OFF_WT);
    u16*   xstg = (u16*)(ws + OFF_XSTG);

    k_prep<<<dim3(2944), dim3(256), 0, stream>>>(netw, wt, xstg, x, px);
    k_sea<<<dim3(16, 16), dim3(256), 0, stream>>>(px, taw, wse, y3);
    k_seb<<<dim3(16), dim3(256), 0, stream>>>(y3, gamma, beta, w1, gl);
    k_fused<<<dim3(14, 128), dim3(256), 0, stream>>>(x, taw, gl, xstg);
    k_conv<<<dim3(7, 2, 128), dim3(256), 0, stream>>>(xstg, wt, netb, out);
}

// Round 19
// 184.814 us; speedup vs baseline: 2.1606x; 2.1606x over previous
//
#include <hip/hip_runtime.h>
#include <hip/hip_bf16.h>

typedef unsigned short u16;
typedef short bf16x8 __attribute__((ext_vector_type(8)));
typedef float f32x4 __attribute__((ext_vector_type(4)));
typedef unsigned short u16x8 __attribute__((ext_vector_type(8)));

#define HW 784
#define PLANE 200704      // 256*784
#define PADPX 900         // 30*30 padded image

// ws layout (bytes)
#define OFF_PX   0          // 128*256 f32
#define OFF_Y3   131072     // 2048 f32
#define OFF_GL   262144     // 128*256 f32 (1+sigmoid)
#define OFF_WT   393216     // 9*8*256*32 bf16 = 1,179,648
#define OFF_XSTG 1572864    // 128*900*256 bf16 = 58,982,400

__device__ __forceinline__ u16 f2b(float f) {
    union { float f; unsigned u; } v; v.f = f;
    unsigned r = v.u + 0x7FFF + ((v.u >> 16) & 1);   // RNE
    return (u16)(r >> 16);
}

typedef __attribute__((address_space(1))) const unsigned int gas_u32;
typedef __attribute__((address_space(3))) unsigned int las_u32;
__device__ __forceinline__ void gload16(const void* g, void* l) {
    __builtin_amdgcn_global_load_lds((gas_u32*)g, (las_u32*)l, 16, 0, 0);
}

// ---------------- k_prep: 3 independent roles split by blockIdx.x
__global__ __launch_bounds__(256) void k_prep(const float* __restrict__ netw, u16* __restrict__ wt,
                                              u16* __restrict__ xstg,
                                              const float* __restrict__ x, float* __restrict__ px) {
    const int bx = blockIdx.x, tid = threadIdx.x;
    if (bx < 2304) {
        int id = bx * 256 + tid;
        int cl = id & 31, co = (id >> 5) & 255, cb = (id >> 13) & 7, tap = id >> 16;
        int ci = cb * 32 + cl;
        wt[id] = f2b(netw[((size_t)co * 256 + ci) * 9 + tap]);
    } else if (bx < 2432) {
        const int nt = bx - 2304;
        for (int it = 0; it < 15; ++it) {
            int cid = it * 256 + tid;
            if (cid < 3712) {
                int pxi = cid >> 5, ch = cid & 31;
                int pidx;
                if (pxi < 30) pidx = pxi;
                else if (pxi < 60) pidx = 29 * 30 + (pxi - 30);
                else { int k = pxi - 60; pidx = (1 + (k >> 1)) * 30 + (k & 1) * 29; }
                *(u16x8*)(xstg + ((size_t)nt * PADPX + pidx) * 256 + ch * 8) = (u16x8){0,0,0,0,0,0,0,0};
            }
        }
    } else {
        const int idx = bx - 2432;
        const int nt = idx >> 2, cg = idx & 3;
        const int wv = tid >> 6, ln = tid & 63;
        for (int i = 0; i < 16; ++i) {
            int c = cg * 64 + wv * 16 + i;
            const float4* xp = (const float4*)(x + (size_t)nt * PLANE + (size_t)c * HW);
            float s = 0.f;
            for (int k = ln; k < 196; k += 64) { float4 v = xp[k]; s += v.x + v.y + v.z + v.w; }
            #pragma unroll
            for (int o = 32; o; o >>= 1) s += __shfl_xor(s, o);
            if (ln == 0) px[nt * 256 + c] = s * (1.f / 784.f);
        }
    }
}

// ---------------- k_sea: 256 blocks = (b, o). Thread = c2. Shift px (shift∘pool==pool∘shift),
// se_conv1d over the faithful [C'][T'] view, tree-reduce over c2.
__global__ __launch_bounds__(256) void k_sea(const float* __restrict__ px,
                                             const float* __restrict__ taw,
                                             const float* __restrict__ wse,
                                             float* __restrict__ y3) {
    const int b = blockIdx.x, o = blockIdx.y;
    const int tid = threadIdx.x;           // = c2
    __shared__ float ps_t[8 * 260];        // [t][c2], pitch 260 (bank-spread)
    __shared__ float red[4][8];
    #pragma unroll
    for (int i = 0; i < 8; ++i) {
        int e = i * 256 + tid;
        int nt = b * 8 + i;
        int c = tid;
        float v = taw[c * 3 + 1] * px[nt * 256 + c];
        if (i > 0) v += taw[c * 3] * px[(nt - 1) * 256 + c];
        if (i < 7) v += taw[c * 3 + 2] * px[(nt + 1) * 256 + c];
        ps_t[(e & 7) * 260 + (e >> 3)] = v;
    }
    __syncthreads();
    const float w0 = wse[(o * 256 + tid) * 3];
    const float w1 = wse[(o * 256 + tid) * 3 + 1];
    const float w2 = wse[(o * 256 + tid) * 3 + 2];
    float v[8];
    #pragma unroll
    for (int t = 0; t < 8; ++t) {
        float a = w1 * ps_t[t * 260 + tid];
        if (t > 0) a += w0 * ps_t[(t - 1) * 260 + tid];
        if (t < 7) a += w2 * ps_t[(t + 1) * 260 + tid];
        v[t] = a;
    }
    #pragma unroll
    for (int t = 0; t < 8; ++t) {
        float s = v[t];
        #pragma unroll
        for (int off = 32; off; off >>= 1) s += __shfl_xor(s, off);
        v[t] = s;
    }
    const int wv = tid >> 6, ln = tid & 63;
    if (ln == 0) {
        #pragma unroll
        for (int t = 0; t < 8; ++t) red[wv][t] = v[t];
    }
    __syncthreads();
    if (tid < 8)
        y3[b * 128 + o * 8 + tid] = red[0][tid] + red[1][tid] + red[2][tid] + red[3][tid];
}

// ---------------- k_seb: BN(batch stats) + relu + 1x1 + sigmoid -> gl = 1+sigmoid
__global__ __launch_bounds__(256) void k_seb(const float* __restrict__ y3,
                                             const float* __restrict__ gamma,
                                             const float* __restrict__ beta,
                                             const float* __restrict__ w1,
                                             float* __restrict__ gl) {
    const int b = blockIdx.x, tid = threadIdx.x;
    __shared__ float y3_l[2048];
    __shared__ float sc[16], bi[16];
    __shared__ float yb[128];
    for (int i = tid; i < 2048; i += 256) y3_l[i] = y3[i];
    __syncthreads();
    if (tid < 16) {
        float s = 0.f, sq = 0.f;
        for (int i = 0; i < 128; ++i) {
            float v = y3_l[(i >> 3) * 128 + tid * 8 + (i & 7)];
            s += v; sq += v * v;
        }
        float m = s * (1.f / 128.f);
        float var = sq * (1.f / 128.f) - m * m;
        float rs = rsqrtf(var + 1e-5f) * gamma[tid];
        sc[tid] = rs; bi[tid] = beta[tid] - m * rs;
    }
    __syncthreads();
    if (tid < 128) {
        int oo = tid >> 3;
        yb[tid] = fmaxf(y3_l[b * 128 + tid] * sc[oo] + bi[oo], 0.f);
    }
    __syncthreads();
    float w1r[16];
    #pragma unroll
    for (int oo = 0; oo < 16; ++oo) w1r[oo] = w1[tid * 16 + oo];
    #pragma unroll
    for (int t = 0; t < 8; ++t) {
        float a = 0.f;
        #pragma unroll
        for (int oo = 0; oo < 16; ++oo) a += w1r[oo] * yb[oo * 8 + t];
        gl[b * 2048 + tid * 8 + t] = 1.f + 1.f / (1.f + __expf(-a));
    }
}

// ---------------- k_fused: temporal shift + gate + transpose -> xstg[nt][padpix][c] bf16
// float4 global loads; LDS pitch 57 (gather 4-way); w-zero plane skips; LINEAR writes
__global__ __launch_bounds__(256) void k_fused(const float* __restrict__ x,
                                               const float* __restrict__ taw,
                                               const float* __restrict__ gl,
                                               u16* __restrict__ xstg) {
    const int pt = blockIdx.x;      // 0..13 (56-pixel strips = 2 rows)
    const int nt = blockIdx.y;
    const int tid = threadIdx.x, wv = tid >> 6, ln = tid & 63;
    const int p0 = pt * 56;
    const int tseg = nt & 7;
    __shared__ float taw_l[768];
    __shared__ float gl_l[256];
    __shared__ __align__(16) u16 xs_l[256 * 57];   // pitch 57: gather lane-stride 4 mod 32
    for (int i = tid; i < 768; i += 256) taw_l[i] = taw[i];
    gl_l[tid] = gl[nt * 256 + tid];
    __syncthreads();
    const int g = ln >> 4;          // 16-lane group -> channel
    const int l = ln & 15;          // float4 index within strip
    const bool act = l < 14;
    for (int j = 0; j < 16; ++j) {
        const int c = j * 16 + wv * 4 + g;
        const float w0 = taw_l[c * 3], w1 = taw_l[c * 3 + 1], w2 = taw_l[c * 3 + 2];
        const float gc = gl_l[c];
        const float* xb = x + (size_t)nt * PLANE + (size_t)c * HW + p0;
        float4 v0 = {0, 0, 0, 0}, vm = {0, 0, 0, 0}, vp = {0, 0, 0, 0};
        if (act) {
            if (w1 != 0.f) v0 = *(const float4*)(xb + l * 4);
            if (w0 != 0.f && tseg > 0) vm = *(const float4*)(xb - PLANE + l * 4);
            if (w2 != 0.f && tseg < 7) vp = *(const float4*)(xb + PLANE + l * 4);
        }
        if (act) {
            xs_l[c * 57 + l * 4 + 0] = f2b((w0 * vm.x + w1 * v0.x + w2 * vp.x) * gc);
            xs_l[c * 57 + l * 4 + 1] = f2b((w0 * vm.y + w1 * v0.y + w2 * vp.y) * gc);
            xs_l[c * 57 + l * 4 + 2] = f2b((w0 * vm.z + w1 * v0.z + w2 * vp.z) * gc);
            xs_l[c * 57 + l * 4 + 3] = f2b((w0 * vm.w + w1 * v0.w + w2 * vp.w) * gc);
        }
    }
    __syncthreads();
    for (int k = 0; k < 7; ++k) {
        int id = k * 256 + tid;        // 0..1791
        int pp = id >> 5;              // 0..55
        int c0 = (id & 31) * 8;
        u16x8 v;
        #pragma unroll
        for (int i = 0; i < 8; ++i) v[i] = xs_l[(c0 + i) * 57 + pp];
        int gp = p0 + pp;
        int r = gp / 28, cc = gp % 28;
        int pidx = (r + 1) * 30 + (cc + 1);
        *(u16x8*)(xstg + ((size_t)nt * PADPX + pidx) * 256 + c0) = v;
    }
}

// ---------------- k_conv: round-17 structure with cb-PAIRED staging: 4 LDS buffers,
// one vmcnt(0)+barrier per 2 cb (4 syncs instead of 8). mf=2, grid 1792, setprio.
__global__ __launch_bounds__(256, 3) void k_conv(const u16* __restrict__ xstg,
                                                 const u16* __restrict__ wt,
                                                 const float* __restrict__ netb,
                                                 float* __restrict__ out) {
    const int pt = blockIdx.x;   // 0..6 : 4 output rows (112 px)
    const int mt = blockIdx.y;   // 0..1 : 128 c_out half
    const int nt = blockIdx.z;   // 0..127
    const int tid = threadIdx.x, wv = tid >> 6, ln = tid & 63;
    __shared__ __align__(16) u16 z_l[4][6144];   // 4 buffers (2 pairs), 12KB each = 48KB
    const int qg = ln >> 4;
    const int p = ln & 15;
    const int g8 = qg * 8;
    int pb[7];
    #pragma unroll
    for (int nf = 0; nf < 7; ++nf) {
        int n = nf * 16 + p;
        pb[nf] = (n / 28) * 30 + (n % 28);     // padded base pos
    }
    f32x4 acc[2][7];
    #pragma unroll
    for (int a = 0; a < 2; ++a)
        #pragma unroll
        for (int b = 0; b < 7; ++b) acc[a][b] = (f32x4){0.f, 0.f, 0.f, 0.f};

    const size_t gbase = ((size_t)nt * PADPX + pt * 120) * 256;   // u16 units
    const int maxpix = 899 - pt * 120;
    int pixl[3], ql[3];
    #pragma unroll
    for (int s = 0; s < 3; ++s) {
        int chunk = (wv * 3 + s) * 64 + ln;
        int px_ = chunk >> 2;
        ql[s] = chunk & 3;
        pixl[s] = px_ < maxpix ? px_ : maxpix;
    }

    auto stage = [&](int cb, int buf) {
        #pragma unroll
        for (int s = 0; s < 3; ++s) {
            const u16* g = xstg + gbase + (size_t)pixl[s] * 256 + cb * 32 + ql[s] * 8;
            gload16(g, &z_l[buf][(wv * 3 + s) * 512]);
        }
    };
    auto aload = [&](int tap, int cb, bf16x8* af) {
        const u16* ab = wt + (((size_t)tap * 8 + cb) * 256 + mt * 128 + wv * 32) * 32;
        af[0] = *(const bf16x8*)(ab + p * 32 + g8);
        af[1] = *(const bf16x8*)(ab + (16 + p) * 32 + g8);
    };

    bf16x8 afc[2], afn[2];
    aload(0, 0, afc);
    stage(0, 0);
    stage(1, 1);
    for (int pair = 0; pair < 4; ++pair) {
        asm volatile("s_waitcnt vmcnt(0)");    // drain gload_lds before barrier
        __syncthreads();
        if (pair < 3) {                        // stage next pair into the other 2 buffers
            stage(pair * 2 + 2, ((pair + 1) & 1) * 2);
            stage(pair * 2 + 3, ((pair + 1) & 1) * 2 + 1);
        }
        #pragma unroll
        for (int cb2 = 0; cb2 < 2; ++cb2) {
            const int cb = pair * 2 + cb2;
            const u16* zl = z_l[(pair & 1) * 2 + cb2];
            #pragma unroll
            for (int tap = 0; tap < 9; ++tap) {
                if (tap < 8) aload(tap + 1, cb, afn);
                else if (cb < 7) aload(0, cb + 1, afn);
                const int po = (tap / 3) * 30 + (tap % 3);
                __builtin_amdgcn_s_setprio(1);
                #pragma unroll
                for (int nf = 0; nf < 7; ++nf) {
                    bf16x8 bf = *(const bf16x8*)&zl[(pb[nf] + po) * 32 + g8];
                    acc[0][nf] = __builtin_amdgcn_mfma_f32_16x16x32_bf16(afc[0], bf, acc[0][nf], 0, 0, 0);
                    acc[1][nf] = __builtin_amdgcn_mfma_f32_16x16x32_bf16(afc[1], bf, acc[1][nf], 0, 0, 0);
                }
                __builtin_amdgcn_s_setprio(0);
                afc[0] = afn[0]; afc[1] = afn[1];
            }
        }
    }
    // epilogue: D layout col=lane&15, row=(lane>>4)*4+i
    const int colp = ln & 15, rowp = (ln >> 4) * 4;
    const int o0 = pt * 112;
    #pragma unroll
    for (int mf = 0; mf < 2; ++mf) {
        #pragma unroll
        for (int i = 0; i < 4; ++i) {
            int co = mt * 128 + wv * 32 + mf * 16 + rowp + i;
            float bias = netb[co];
            float* ob = out + ((size_t)nt * 256 + co) * HW + o0;
            #pragma unroll
            for (int nf = 0; nf < 7; ++nf)
                ob[nf * 16 + colp] = acc[mf][nf][i] + bias;
        }
    }
}

extern "C" void kernel_launch(void* const* d_in, const int* in_sizes, int n_in,
                              void* d_out, int out_size, void* d_ws, size_t ws_size,
                              hipStream_t stream) {
    const float* x     = (const float*)d_in[0];
    const float* taw   = (const float*)d_in[1];
    const float* wse   = (const float*)d_in[2];
    const float* gamma = (const float*)d_in[3];
    const float* beta  = (const float*)d_in[4];
    const float* w1    = (const float*)d_in[5];
    const float* netw  = (const float*)d_in[6];
    const float* netb  = (const float*)d_in[7];
    float* out = (float*)d_out;
    char* ws = (char*)d_ws;
    float* px   = (float*)(ws + OFF_PX);
    float* y3   = (float*)(ws + OFF_Y3);
    float* gl   = (float*)(ws + OFF_GL);
    u16*   wt   = (u16*)(ws + OFF_WT);
    u16*   xstg = (u16*)(ws + OFF_XSTG);

    k_prep<<<dim3(2944), dim3(256), 0, stream>>>(netw, wt, xstg, x, px);
    k_sea<<<dim3(16, 16), dim3(256), 0, stream>>>(px, taw, wse, y3);
    k_seb<<<dim3(16), dim3(256), 0, stream>>>(y3, gamma, beta, w1, gl);
    k_fused<<<dim3(14, 128), dim3(256), 0, stream>>>(x, taw, gl, xstg);
    k_conv<<<dim3(7, 2, 128), dim3(256), 0, stream>>>(xstg, wt, netb, out);
}

// Round 20
// 184.462 us; speedup vs baseline: 2.1647x; 1.0019x over previous
//
#include <hip/hip_runtime.h>
#include <hip/hip_bf16.h>

typedef unsigned short u16;
typedef short bf16x8 __attribute__((ext_vector_type(8)));
typedef float f32x4 __attribute__((ext_vector_type(4)));
typedef unsigned short u16x8 __attribute__((ext_vector_type(8)));

#define HW 784
#define PLANE 200704      // 256*784
#define PADPX 900         // 30*30 padded image
#define QPL 7200          // u16 per slot-plane: 900*8
#define NTPL 230400       // u16 per nt: 32*7200

// ws layout (bytes)
#define OFF_PX   0          // 128*256 f32
#define OFF_Y3   131072     // 2048 f32
#define OFF_GL   262144     // 128*256 f32 (1+sigmoid)
#define OFF_WT   393216     // 9*8*256*32 bf16 = 1,179,648
#define OFF_XSTG 1572864    // 128*900*256 bf16 = 58,982,400

__device__ __forceinline__ u16 f2b(float f) {
    union { float f; unsigned u; } v; v.f = f;
    unsigned r = v.u + 0x7FFF + ((v.u >> 16) & 1);   // RNE
    return (u16)(r >> 16);
}

typedef __attribute__((address_space(1))) const unsigned int gas_u32;
typedef __attribute__((address_space(3))) unsigned int las_u32;
__device__ __forceinline__ void gload16(const void* g, void* l) {
    __builtin_amdgcn_global_load_lds((gas_u32*)g, (las_u32*)l, 16, 0, 0);
}

// ---------------- k_prep: 3 independent roles split by blockIdx.x
__global__ __launch_bounds__(256) void k_prep(const float* __restrict__ netw, u16* __restrict__ wt,
                                              u16* __restrict__ xstg,
                                              const float* __restrict__ x, float* __restrict__ px) {
    const int bx = blockIdx.x, tid = threadIdx.x;
    if (bx < 2304) {
        int id = bx * 256 + tid;
        int cl = id & 31, co = (id >> 5) & 255, cb = (id >> 13) & 7, tap = id >> 16;
        int ci = cb * 32 + cl;
        wt[id] = f2b(netw[((size_t)co * 256 + ci) * 9 + tap]);
    } else if (bx < 2432) {
        const int nt = bx - 2304;
        for (int it = 0; it < 15; ++it) {
            int cid = it * 256 + tid;
            if (cid < 3712) {
                int pxi = cid >> 5, slot = cid & 31;
                int pidx;
                if (pxi < 30) pidx = pxi;
                else if (pxi < 60) pidx = 29 * 30 + (pxi - 30);
                else { int k = pxi - 60; pidx = (1 + (k >> 1)) * 30 + (k & 1) * 29; }
                *(u16x8*)(xstg + (size_t)nt * NTPL + slot * QPL + pidx * 8) = (u16x8){0,0,0,0,0,0,0,0};
            }
        }
    } else {
        const int idx = bx - 2432;
        const int nt = idx >> 2, cg = idx & 3;
        const int wv = tid >> 6, ln = tid & 63;
        for (int i = 0; i < 16; ++i) {
            int c = cg * 64 + wv * 16 + i;
            const float4* xp = (const float4*)(x + (size_t)nt * PLANE + (size_t)c * HW);
            float s = 0.f;
            for (int k = ln; k < 196; k += 64) { float4 v = xp[k]; s += v.x + v.y + v.z + v.w; }
            #pragma unroll
            for (int o = 32; o; o >>= 1) s += __shfl_xor(s, o);
            if (ln == 0) px[nt * 256 + c] = s * (1.f / 784.f);
        }
    }
}

// ---------------- k_sea: 256 blocks = (b, o). Thread = c2. Shift px (shift∘pool==pool∘shift),
// se_conv1d over the faithful [C'][T'] view, tree-reduce over c2.
__global__ __launch_bounds__(256) void k_sea(const float* __restrict__ px,
                                             const float* __restrict__ taw,
                                             const float* __restrict__ wse,
                                             float* __restrict__ y3) {
    const int b = blockIdx.x, o = blockIdx.y;
    const int tid = threadIdx.x;           // = c2
    __shared__ float ps_t[8 * 260];        // [t][c2], pitch 260 (bank-spread)
    __shared__ float red[4][8];
    #pragma unroll
    for (int i = 0; i < 8; ++i) {
        int e = i * 256 + tid;
        int nt = b * 8 + i;
        int c = tid;
        float v = taw[c * 3 + 1] * px[nt * 256 + c];
        if (i > 0) v += taw[c * 3] * px[(nt - 1) * 256 + c];
        if (i < 7) v += taw[c * 3 + 2] * px[(nt + 1) * 256 + c];
        ps_t[(e & 7) * 260 + (e >> 3)] = v;
    }
    __syncthreads();
    const float w0 = wse[(o * 256 + tid) * 3];
    const float w1 = wse[(o * 256 + tid) * 3 + 1];
    const float w2 = wse[(o * 256 + tid) * 3 + 2];
    float v[8];
    #pragma unroll
    for (int t = 0; t < 8; ++t) {
        float a = w1 * ps_t[t * 260 + tid];
        if (t > 0) a += w0 * ps_t[(t - 1) * 260 + tid];
        if (t < 7) a += w2 * ps_t[(t + 1) * 260 + tid];
        v[t] = a;
    }
    #pragma unroll
    for (int t = 0; t < 8; ++t) {
        float s = v[t];
        #pragma unroll
        for (int off = 32; off; off >>= 1) s += __shfl_xor(s, off);
        v[t] = s;
    }
    const int wv = tid >> 6, ln = tid & 63;
    if (ln == 0) {
        #pragma unroll
        for (int t = 0; t < 8; ++t) red[wv][t] = v[t];
    }
    __syncthreads();
    if (tid < 8)
        y3[b * 128 + o * 8 + tid] = red[0][tid] + red[1][tid] + red[2][tid] + red[3][tid];
}

// ---------------- k_seb: BN(batch stats) + relu + 1x1 + sigmoid -> gl = 1+sigmoid
__global__ __launch_bounds__(256) void k_seb(const float* __restrict__ y3,
                                             const float* __restrict__ gamma,
                                             const float* __restrict__ beta,
                                             const float* __restrict__ w1,
                                             float* __restrict__ gl) {
    const int b = blockIdx.x, tid = threadIdx.x;
    __shared__ float y3_l[2048];
    __shared__ float sc[16], bi[16];
    __shared__ float yb[128];
    for (int i = tid; i < 2048; i += 256) y3_l[i] = y3[i];
    __syncthreads();
    if (tid < 16) {
        float s = 0.f, sq = 0.f;
        for (int i = 0; i < 128; ++i) {
            float v = y3_l[(i >> 3) * 128 + tid * 8 + (i & 7)];
            s += v; sq += v * v;
        }
        float m = s * (1.f / 128.f);
        float var = sq * (1.f / 128.f) - m * m;
        float rs = rsqrtf(var + 1e-5f) * gamma[tid];
        sc[tid] = rs; bi[tid] = beta[tid] - m * rs;
    }
    __syncthreads();
    if (tid < 128) {
        int oo = tid >> 3;
        yb[tid] = fmaxf(y3_l[b * 128 + tid] * sc[oo] + bi[oo], 0.f);
    }
    __syncthreads();
    float w1r[16];
    #pragma unroll
    for (int oo = 0; oo < 16; ++oo) w1r[oo] = w1[tid * 16 + oo];
    #pragma unroll
    for (int t = 0; t < 8; ++t) {
        float a = 0.f;
        #pragma unroll
        for (int oo = 0; oo < 16; ++oo) a += w1r[oo] * yb[oo * 8 + t];
        gl[b * 2048 + tid * 8 + t] = 1.f + 1.f / (1.f + __expf(-a));
    }
}

// ---------------- k_fused: temporal shift + gate + transpose -> xstg quarter-plane layout
// xstg[nt][slot=c>>3][pidx][c&7] bf16 — 448B contiguous runs per slot write.
__global__ __launch_bounds__(256) void k_fused(const float* __restrict__ x,
                                               const float* __restrict__ taw,
                                               const float* __restrict__ gl,
                                               u16* __restrict__ xstg) {
    const int pt = blockIdx.x;      // 0..13 (56-pixel strips = 2 rows)
    const int nt = blockIdx.y;
    const int tid = threadIdx.x, wv = tid >> 6, ln = tid & 63;
    const int p0 = pt * 56;
    const int tseg = nt & 7;
    __shared__ float taw_l[768];
    __shared__ float gl_l[256];
    __shared__ __align__(16) u16 xs_l[256 * 57];   // pitch 57: gather lane-stride 4 mod 32
    for (int i = tid; i < 768; i += 256) taw_l[i] = taw[i];
    gl_l[tid] = gl[nt * 256 + tid];
    __syncthreads();
    const int g = ln >> 4;          // 16-lane group -> channel
    const int l = ln & 15;          // float4 index within strip
    const bool act = l < 14;
    for (int j = 0; j < 16; ++j) {
        const int c = j * 16 + wv * 4 + g;
        const float w0 = taw_l[c * 3], w1 = taw_l[c * 3 + 1], w2 = taw_l[c * 3 + 2];
        const float gc = gl_l[c];
        const float* xb = x + (size_t)nt * PLANE + (size_t)c * HW + p0;
        float4 v0 = {0, 0, 0, 0}, vm = {0, 0, 0, 0}, vp = {0, 0, 0, 0};
        if (act) {
            if (w1 != 0.f) v0 = *(const float4*)(xb + l * 4);
            if (w0 != 0.f && tseg > 0) vm = *(const float4*)(xb - PLANE + l * 4);
            if (w2 != 0.f && tseg < 7) vp = *(const float4*)(xb + PLANE + l * 4);
        }
        if (act) {
            xs_l[c * 57 + l * 4 + 0] = f2b((w0 * vm.x + w1 * v0.x + w2 * vp.x) * gc);
            xs_l[c * 57 + l * 4 + 1] = f2b((w0 * vm.y + w1 * v0.y + w2 * vp.y) * gc);
            xs_l[c * 57 + l * 4 + 2] = f2b((w0 * vm.z + w1 * v0.z + w2 * vp.z) * gc);
            xs_l[c * 57 + l * 4 + 3] = f2b((w0 * vm.w + w1 * v0.w + w2 * vp.w) * gc);
        }
    }
    __syncthreads();
    for (int k = 0; k < 7; ++k) {
        int id = k * 256 + tid;        // 0..1791 = 32 slots x 56 px
        int slot = id / 56;            // channel octet 0..31
        int pp = id % 56;
        u16x8 v;
        #pragma unroll
        for (int i = 0; i < 8; ++i) v[i] = xs_l[(slot * 8 + i) * 57 + pp];
        int gp = p0 + pp;
        int r = gp / 28, cc = gp % 28;
        int pidx = (r + 1) * 30 + (cc + 1);
        *(u16x8*)(xstg + (size_t)nt * NTPL + slot * QPL + pidx * 8) = v;
    }
}

// ---------------- k_conv: round-17 structure; LDS z now quarter-plane [q][192px][8ch]
// (stage = consecutive-16B global reads per chunk; B-read = 2-way bank access, free).
__global__ __launch_bounds__(256, 3) void k_conv(const u16* __restrict__ xstg,
                                                 const u16* __restrict__ wt,
                                                 const float* __restrict__ netb,
                                                 float* __restrict__ out) {
    const int pt = blockIdx.x;   // 0..6 : 4 output rows (112 px)
    const int mt = blockIdx.y;   // 0..1 : 128 c_out half
    const int nt = blockIdx.z;   // 0..127
    const int tid = threadIdx.x, wv = tid >> 6, ln = tid & 63;
    __shared__ __align__(16) u16 z_l[2][6144];   // [q 4][pix 192][8ch], 12KB each
    const int qg = ln >> 4;
    const int p = ln & 15;
    int pb[7];
    #pragma unroll
    for (int nf = 0; nf < 7; ++nf) {
        int n = nf * 16 + p;
        pb[nf] = (n / 28) * 30 + (n % 28);     // padded base pos
    }
    f32x4 acc[2][7];
    #pragma unroll
    for (int a = 0; a < 2; ++a)
        #pragma unroll
        for (int b = 0; b < 7; ++b) acc[a][b] = (f32x4){0.f, 0.f, 0.f, 0.f};

    const size_t qbase = (size_t)nt * NTPL + pt * 960;   // u16; pixel base pt*120 within planes
    const int maxpix = 899 - pt * 120;

    // stage one cb-slice: chunk k = wv*3+s covers quarter q=wv, pixels s*64..s*64+63;
    // global source consecutive 16B per lane (quarter-plane layout).
    auto stage = [&](int cb, int buf) {
        #pragma unroll
        for (int s = 0; s < 3; ++s) {
            int pix = s * 64 + ln;
            int psrc = pix < maxpix ? pix : maxpix;
            const u16* g = xstg + qbase + (size_t)(cb * 4 + wv) * QPL + psrc * 8;
            gload16(g, &z_l[buf][(wv * 3 + s) * 512]);
        }
    };
    auto aload = [&](int tap, int cb, bf16x8* af) {
        const u16* ab = wt + (((size_t)tap * 8 + cb) * 256 + mt * 128 + wv * 32) * 32;
        af[0] = *(const bf16x8*)(ab + p * 32 + qg * 8);
        af[1] = *(const bf16x8*)(ab + (16 + p) * 32 + qg * 8);
    };

    bf16x8 afc[2], afn[2];
    aload(0, 0, afc);
    stage(0, 0);
    for (int cb = 0; cb < 8; ++cb) {
        asm volatile("s_waitcnt vmcnt(0)");    // drain gload_lds before barrier
        __syncthreads();
        if (cb < 7) stage(cb + 1, (cb + 1) & 1);
        const u16* zl = z_l[cb & 1];
        #pragma unroll
        for (int tap = 0; tap < 9; ++tap) {
            if (tap < 8) aload(tap + 1, cb, afn);
            else if (cb < 7) aload(0, cb + 1, afn);
            const int po = (tap / 3) * 30 + (tap % 3);
            __builtin_amdgcn_s_setprio(1);
            #pragma unroll
            for (int nf = 0; nf < 7; ++nf) {
                bf16x8 bf = *(const bf16x8*)&zl[qg * 1536 + (pb[nf] + po) * 8];
                acc[0][nf] = __builtin_amdgcn_mfma_f32_16x16x32_bf16(afc[0], bf, acc[0][nf], 0, 0, 0);
                acc[1][nf] = __builtin_amdgcn_mfma_f32_16x16x32_bf16(afc[1], bf, acc[1][nf], 0, 0, 0);
            }
            __builtin_amdgcn_s_setprio(0);
            afc[0] = afn[0]; afc[1] = afn[1];
        }
    }
    // epilogue: D layout col=lane&15, row=(lane>>4)*4+i
    const int colp = ln & 15, rowp = (ln >> 4) * 4;
    const int o0 = pt * 112;
    #pragma unroll
    for (int mf = 0; mf < 2; ++mf) {
        #pragma unroll
        for (int i = 0; i < 4; ++i) {
            int co = mt * 128 + wv * 32 + mf * 16 + rowp + i;
            float bias = netb[co];
            float* ob = out + ((size_t)nt * 256 + co) * HW + o0;
            #pragma unroll
            for (int nf = 0; nf < 7; ++nf)
                ob[nf * 16 + colp] = acc[mf][nf][i] + bias;
        }
    }
}

extern "C" void kernel_launch(void* const* d_in, const int* in_sizes, int n_in,
                              void* d_out, int out_size, void* d_ws, size_t ws_size,
                              hipStream_t stream) {
    const float* x     = (const float*)d_in[0];
    const float* taw   = (const float*)d_in[1];
    const float* wse   = (const float*)d_in[2];
    const float* gamma = (const float*)d_in[3];
    const float* beta  = (const float*)d_in[4];
    const float* w1    = (const float*)d_in[5];
    const float* netw  = (const float*)d_in[6];
    const float* netb  = (const float*)d_in[7];
    float* out = (float*)d_out;
    char* ws = (char*)d_ws;
    float* px   = (float*)(ws + OFF_PX);
    float* y3   = (float*)(ws + OFF_Y3);
    float* gl   = (float*)(ws + OFF_GL);
    u16*   wt   = (u16*)(ws + OFF_WT);
    u16*   xstg = (u16*)(ws + OFF_XSTG);

    k_prep<<<dim3(2944), dim3(256), 0, stream>>>(netw, wt, xstg, x, px);
    k_sea<<<dim3(16, 16), dim3(256), 0, stream>>>(px, taw, wse, y3);
    k_seb<<<dim3(16), dim3(256), 0, stream>>>(y3, gamma, beta, w1, gl);
    k_fused<<<dim3(14, 128), dim3(256), 0, stream>>>(x, taw, gl, xstg);
    k_conv<<<dim3(7, 2, 128), dim3(256), 0, stream>>>(xstg, wt, netb, out);
}